// Round 4
// baseline (223.529 us; speedup 1.0000x reference)
//
#include <hip/hip_runtime.h>

// ZNCC fused streaming kernel. [16,3,512,512] f32 -> [16,1,512,512] f32.
// 5x5 box means, zero pad, /25; second 5x5 box over centered products.
//
// Register-resident vertical rolling sums; horizontal sums in registers from
// overlapping per-lane loads (halo via L1/L2, not LDS).
// Block = 192 threads = 3 waves, one per channel, for one (b, seg, strip).
// HS=8 output rows per segment -> 2048 blocks -> 8 blocks/CU (75% occ cap).
// The 16-iteration row pipeline is fully unrolled: all phase conditionals and
// the k%5 queue index are compile-time.
// LDS: only an 8KB ncc accumulator (ds atomics across the 3 channel waves).

constexpr int W = 512, H = 512, Cn = 3, Bn = 16;
constexpr int HS = 8;        // output rows per segment
constexpr int STRIPW = 256;  // output cols per wave strip
constexpr int NOUT = 4;      // output cols per lane

__device__ __forceinline__ void load_row12(const float* base, bool okA, bool okC,
                                           float* d) {
    // cols [c0, c0+12); A/C float4s may be fully out of image (lane 0 / lane 63 only)
    float4 a = {0.f, 0.f, 0.f, 0.f};
    float4 c = {0.f, 0.f, 0.f, 0.f};
    if (okA) a = *(const float4*)(base);
    float4 b = *(const float4*)(base + 4);
    if (okC) c = *(const float4*)(base + 8);
    d[0] = a.x; d[1] = a.y; d[2]  = a.z; d[3]  = a.w;
    d[4] = b.x; d[5] = b.y; d[6]  = b.z; d[7]  = b.w;
    d[8] = c.x; d[9] = c.y; d[10] = c.z; d[11] = c.w;
}

__global__ __launch_bounds__(192) void zncc_stream(const float* __restrict__ xg,
                                                   const float* __restrict__ yg,
                                                   float* __restrict__ outg) {
    __shared__ float acc[HS * STRIPW];  // 8 KB

    const int tid  = threadIdx.x;
    const int lane = tid & 63;
    const int ch   = tid >> 6;          // wave -> channel
    const int bx   = blockIdx.x;        // seg*2 + strip
    const int seg  = bx >> 1;
    const int strip = bx & 1;
    const int b    = blockIdx.y;
    const int o0   = seg * HS;

    // zero the LDS accumulator
    for (int i = tid; i < HS * STRIPW / 4; i += 192)
        ((float4*)acc)[i] = make_float4(0.f, 0.f, 0.f, 0.f);
    __syncthreads();

    const float* __restrict__ xp = xg + ((size_t)(b * Cn + ch)) * (H * W);
    const float* __restrict__ yp = yg + ((size_t)(b * Cn + ch)) * (H * W);

    const int m0 = strip * STRIPW + lane * NOUT;  // first output col
    const int c0 = m0 - 4;                        // first raw col (12-wide span)
    const bool okA = (c0 >= 0);                   // fails only lane 0, strip 0
    const bool okC = (c0 + 8 < W);                // fails only lane 63, strip 1

    // product-column validity masks (cols m0-2+i)
    float pm[8];
#pragma unroll
    for (int i = 0; i < 8; ++i) {
        int col = m0 - 2 + i;
        pm[i] = (col >= 0 && col < W) ? 1.f : 0.f;
    }

    float vsx[12], vsy[12];                        // rolling vertical 5-row raw sums
    float qxx[5][4], qxy[5][4], qyy[5][4];         // hp queue (5-deep)
    float oxx[4], oxy[4], oyy[4];                  // rolling vertical hp sums
#pragma unroll
    for (int i = 0; i < 12; ++i) { vsx[i] = 0.f; vsy[i] = 0.f; }
#pragma unroll
    for (int s = 0; s < 5; ++s)
#pragma unroll
        for (int j = 0; j < 4; ++j) { qxx[s][j] = 0.f; qxy[s][j] = 0.f; qyy[s][j] = 0.f; }
#pragma unroll
    for (int j = 0; j < 4; ++j) { oxx[j] = 0.f; oxy[j] = 0.f; oyy[j] = 0.f; }

    // iter k: load raw row L = o0-4+k; vsum covers rows L-4..L (center V = L-2);
    // products/hp at row V (k>=4); output row O = L-4 = o0-8+k (k>=8).
    // Fully unrolled: k, u=k%5, and phase conditions are compile-time.
#pragma unroll
    for (int k = 0; k < HS + 8; ++k) {
        const int u = k % 5;
        const int L = o0 - 4 + k;

        // subtract row L-5 — only if it was added in this segment's history
        if (k >= 5) {
            const int Lold = L - 5;
            if (Lold >= 0) {  // uniform (seg 0 edge only)
                float ox[12], oy[12];
                load_row12(xp + (size_t)Lold * W + c0, okA, okC, ox);
                load_row12(yp + (size_t)Lold * W + c0, okA, okC, oy);
#pragma unroll
                for (int i = 0; i < 12; ++i) { vsx[i] -= ox[i]; vsy[i] -= oy[i]; }
            }
        }
        // add new row L
        if (L >= 0 && L < H) {  // uniform (first/last seg edges only)
            float nx[12], ny[12];
            load_row12(xp + (size_t)L * W + c0, okA, okC, nx);
            load_row12(yp + (size_t)L * W + c0, okA, okC, ny);
#pragma unroll
            for (int i = 0; i < 12; ++i) { vsx[i] += nx[i]; vsy[i] += ny[i]; }
        }

        if (k >= 4) {
            // retire hp row V-5 from rolling output sums (slot u, to be overwritten)
#pragma unroll
            for (int j = 0; j < 4; ++j) {
                oxx[j] -= qxx[u][j]; oxy[j] -= qxy[u][j]; oyy[j] -= qyy[u][j];
            }
            const int V = L - 2;
            if (V >= 0 && V < H) {  // uniform
                // 25-sums (means*25) at mid cols m0-2+i via incremental h-sum
                float mx[8], my[8];
                mx[0] = vsx[0] + vsx[1] + vsx[2] + vsx[3] + vsx[4];
                my[0] = vsy[0] + vsy[1] + vsy[2] + vsy[3] + vsy[4];
#pragma unroll
                for (int i = 1; i < 8; ++i) {
                    mx[i] = mx[i - 1] - vsx[i - 1] + vsx[i + 4];
                    my[i] = my[i - 1] - vsy[i - 1] + vsy[i + 4];
                }
                // center row raw (re-read; L1/L2 hot — loaded 2 iters ago)
                float cx[12], cyv[12];
                load_row12(xp + (size_t)V * W + c0, okA, okC, cx);
                load_row12(yp + (size_t)V * W + c0, okA, okC, cyv);

                float pxx[8], pxy[8], pyy[8];
#pragma unroll
                for (int i = 0; i < 8; ++i) {
                    float xc = (cx[i + 2]  - mx[i] * 0.04f) * pm[i];
                    float yc = (cyv[i + 2] - my[i] * 0.04f) * pm[i];
                    pxx[i] = xc * xc; pxy[i] = xc * yc; pyy[i] = yc * yc;
                }
                // horizontal 5-sum of products -> 4 outputs; push + add to rolling sums
                float h;
                h = pxx[0] + pxx[1] + pxx[2] + pxx[3] + pxx[4];
                qxx[u][0] = h; oxx[0] += h;
#pragma unroll
                for (int j = 1; j < 4; ++j) {
                    h = h - pxx[j - 1] + pxx[j + 4]; qxx[u][j] = h; oxx[j] += h;
                }
                h = pxy[0] + pxy[1] + pxy[2] + pxy[3] + pxy[4];
                qxy[u][0] = h; oxy[0] += h;
#pragma unroll
                for (int j = 1; j < 4; ++j) {
                    h = h - pxy[j - 1] + pxy[j + 4]; qxy[u][j] = h; oxy[j] += h;
                }
                h = pyy[0] + pyy[1] + pyy[2] + pyy[3] + pyy[4];
                qyy[u][0] = h; oyy[0] += h;
#pragma unroll
                for (int j = 1; j < 4; ++j) {
                    h = h - pyy[j - 1] + pyy[j + 4]; qyy[u][j] = h; oyy[j] += h;
                }
            } else {
                // padding row: products are zero
#pragma unroll
                for (int j = 0; j < 4; ++j) { qxx[u][j] = 0.f; qxy[u][j] = 0.f; qyy[u][j] = 0.f; }
            }

            if (k >= 8) {
                const int r = k - 8;  // output row within segment (compile-time)
#pragma unroll
                for (int j = 0; j < 4; ++j) {
                    // ncc = (Sxy/25) / (sqrt(Sxx/25)*sqrt(Syy/25) + 1e-8)
                    //     = Sxy / (sqrt(Sxx*Syy) + 25e-8)
                    float rad = fmaxf(oxx[j] * oyy[j], 0.f);  // guard rolling drift
                    float s = sqrtf(rad) + 2.5e-7f;
                    float ncc = oxy[j] * __builtin_amdgcn_rcpf(s);
                    atomicAdd(&acc[r * STRIPW + lane * NOUT + j], ncc);
                }
            }
        }
    }

    __syncthreads();
    // writeout: mean over 3 channels
    const float inv3 = 1.f / 3.f;
    float* op = outg + (size_t)b * (H * W);
    for (int i = tid; i < HS * STRIPW / 4; i += 192) {
        float4 v = ((const float4*)acc)[i];
        v.x *= inv3; v.y *= inv3; v.z *= inv3; v.w *= inv3;
        int r = i / (STRIPW / 4);
        int c4 = i - r * (STRIPW / 4);
        *(float4*)(op + (size_t)(o0 + r) * W + strip * STRIPW + c4 * 4) = v;
    }
}

extern "C" void kernel_launch(void* const* d_in, const int* in_sizes, int n_in,
                              void* d_out, int out_size, void* d_ws, size_t ws_size,
                              hipStream_t stream) {
    const float* x = (const float*)d_in[0];
    const float* y = (const float*)d_in[1];
    float* out = (float*)d_out;
    dim3 grid((H / HS) * (W / STRIPW), Bn);  // 128 x 16 = 2048 blocks
    zncc_stream<<<grid, 192, 0, stream>>>(x, y, out);
}

// Round 6
// 204.815 us; speedup vs baseline: 1.0914x; 1.0914x over previous
//
#include <hip/hip_runtime.h>

// ZNCC fused kernel. [16,3,512,512] f32 -> [16,1,512,512] f32.
// 5x5 box means (zero pad, /25); second 5x5 box over centered products.
//
// R6 = R5 (per-wave LDS row ring) + compiler memory fences.
// Each global byte is loaded ONCE per wave (coalesced float4); old-row /
// center-row re-reads and the 3x column overlap come from LDS.
// Block = 192 threads = 3 waves (one per channel); ring is wave-private ->
// no s_barrier in the main loop. BUT cross-lane LDS reuse (lane i reads what
// lanes i+1/i+2 wrote) is invisible to LLVM alias analysis, so the write/read
// of the SAME ring slot must be separated by asm memory fences (zero-cost,
// compiler-ordering only; HW DS ops are in-order per wave).

constexpr int W = 512, H = 512, Cn = 3, Bn = 16;
constexpr int HS = 16;        // output rows per segment
constexpr int STRIPW = 256;   // output cols per wave strip
constexpr int RW = 264;       // ring row width (cols s0-4 .. s0+259)
constexpr int RING_CH = 5 * 2 * RW;                  // 2640 floats per channel
constexpr int ACC_OFF = Cn * RING_CH;                // 7920
constexpr int SMEM_FLOATS = ACC_OFF + HS * STRIPW;   // 12016 floats = 48064 B

#define LDS_FENCE() asm volatile("" ::: "memory")

__global__ __launch_bounds__(192) void zncc_ring(const float* __restrict__ xg,
                                                 const float* __restrict__ yg,
                                                 float* __restrict__ outg) {
    __shared__ float smem[SMEM_FLOATS];

    const int tid   = threadIdx.x;
    const int lane  = tid & 63;
    const int ch    = tid >> 6;
    const int bx    = blockIdx.x;   // seg*2 + strip
    const int seg   = bx >> 1;
    const int strip = bx & 1;
    const int b     = blockIdx.y;
    const int o0    = seg * HS;
    const int s0    = strip * STRIPW;

    float* acc = smem + ACC_OFF;
    for (int i = tid; i < HS * STRIPW / 4; i += 192)
        ((float4*)acc)[i] = make_float4(0.f, 0.f, 0.f, 0.f);
    __syncthreads();

    const float* __restrict__ xp = xg + (size_t)(b * Cn + ch) * (H * W);
    const float* __restrict__ yp = yg + (size_t)(b * Cn + ch) * (H * W);

    float* ring = smem + ch * RING_CH;
    const int rs = 4 * lane;                 // per-lane span start in ring row

    // cooperative row staging: lane writes float4 #lane (ring col 4*lane,
    // global col g0); lanes 0..1 also write float4 #(64+lane) (ring col
    // 256+4*lane, global col g1). float4s never straddle the image edge.
    const int g0 = s0 - 4 + 4 * lane;
    const int g1 = s0 + 252 + 4 * lane;
    const bool ok0 = (g0 >= 0) && (g0 + 3 < W);   // false only strip0 lane0
    const bool ex  = (lane < 2);
    const bool ok1 = ex && (g1 + 3 < W);          // false for strip1 lane1

    // zero-product masks for out-of-image product cols (cols m0-2+i)
    const float pmA = (strip == 0 && lane == 0) ? 0.f : 1.f;   // i = 0,1
    const float pmB = (strip == 1 && lane == 63) ? 0.f : 1.f;  // i = 6,7

    float vsx[12], vsy[12];        // rolling vertical 5-row raw sums (span)
#pragma unroll
    for (int i = 0; i < 12; ++i) { vsx[i] = 0.f; vsy[i] = 0.f; }
    float hq[5][3][4];             // hp history [slot][xx,xy,yy][j]
#pragma unroll
    for (int s = 0; s < 5; ++s)
#pragma unroll
        for (int t = 0; t < 3; ++t)
#pragma unroll
            for (int j = 0; j < 4; ++j) hq[s][t][j] = 0.f;

    float4 pfx0, pfy0, pfx1, pfy1;  // prefetched row (global -> regs)

    auto loadrow = [&](int L) {
        pfx0 = pfy0 = pfx1 = pfy1 = make_float4(0.f, 0.f, 0.f, 0.f);
        if (L >= 0 && L < H) {      // uniform
            const float* xr = xp + ((size_t)L << 9);
            const float* yr = yp + ((size_t)L << 9);
            if (ok0) { pfx0 = *(const float4*)(xr + g0); pfy0 = *(const float4*)(yr + g0); }
            if (ok1) { pfx1 = *(const float4*)(xr + g1); pfy1 = *(const float4*)(yr + g1); }
        }
    };
    auto writerow = [&](int off) {  // off = slot*2*RW (float index)
        *(float4*)(ring + off + rs) = pfx0;
        *(float4*)(ring + off + RW + rs) = pfy0;
        if (ex) {
            *(float4*)(ring + off + 256 + 4 * lane) = pfx1;
            *(float4*)(ring + off + RW + 256 + 4 * lane) = pfy1;
        }
    };
    auto readspan = [&](int off, float* dx, float* dy) {
        float4 a0 = *(const float4*)(ring + off + rs);
        float4 a1 = *(const float4*)(ring + off + rs + 4);
        float4 a2 = *(const float4*)(ring + off + rs + 8);
        float4 b0 = *(const float4*)(ring + off + RW + rs);
        float4 b1 = *(const float4*)(ring + off + RW + rs + 4);
        float4 b2 = *(const float4*)(ring + off + RW + rs + 8);
        dx[0]=a0.x; dx[1]=a0.y; dx[2]=a0.z; dx[3]=a0.w;
        dx[4]=a1.x; dx[5]=a1.y; dx[6]=a1.z; dx[7]=a1.w;
        dx[8]=a2.x; dx[9]=a2.y; dx[10]=a2.z; dx[11]=a2.w;
        dy[0]=b0.x; dy[1]=b0.y; dy[2]=b0.z; dy[3]=b0.w;
        dy[4]=b1.x; dy[5]=b1.y; dy[6]=b1.z; dy[7]=b1.w;
        dy[8]=b2.x; dy[9]=b2.y; dy[10]=b2.z; dy[11]=b2.w;
    };

    // iter k: stage row L = o0-4+k into slot k%5; vsum covers rows L-4..L;
    // products/hp at center V = L-2 (k>=4, ring slot (k-2)%5);
    // output row O = L-4 = o0+k-8 (k>=8).
    loadrow(o0 - 4);  // prefetch k=0's row

    // prologue k = 0..3: stage + vsum only
#pragma unroll
    for (int k = 0; k < 4; ++k) {
        const int off = 2 * RW * k;   // slot = k
        writerow(off);
        loadrow(o0 - 3 + k);
        LDS_FENCE();                  // write (all lanes) before cross-lane read
        float nsx[12], nsy[12];
        readspan(off, nsx, nsy);
#pragma unroll
        for (int i = 0; i < 12; ++i) { vsx[i] += nsx[i]; vsy[i] += nsy[i]; }
    }

    // main: k = 4..23  (bq rolled to keep the body in icache; u unrolled so
    // ring slots and hq indices are compile-time)
#pragma unroll 1
    for (int bq = 0; bq < 4; ++bq) {
#pragma unroll
        for (int u = 0; u < 5; ++u) {
            const int k = 4 + 5 * bq + u;
            const int slot = (4 + u) % 5;         // static
            const int off  = 2 * RW * slot;       // static
            const int coff = 2 * RW * ((2 + u) % 5);  // center slot, static
            const int L = o0 - 4 + k;

            if (k >= 5) {  // uniform; false only bq=0,u=0
                float osx[12], osy[12];
                readspan(off, osx, osy);          // old row L-5 (pre-overwrite)
#pragma unroll
                for (int i = 0; i < 12; ++i) { vsx[i] -= osx[i]; vsy[i] -= osy[i]; }
            }
            LDS_FENCE();                          // old-row reads before overwrite
            writerow(off);                        // stage row L (prefetched)
            LDS_FENCE();                          // write before cross-lane read
            loadrow(L + 1);                       // prefetch next (self-masked)
            float nsx[12], nsy[12];
            readspan(off, nsx, nsy);
#pragma unroll
            for (int i = 0; i < 12; ++i) { vsx[i] += nsx[i]; vsy[i] += nsy[i]; }

            const int V = L - 2;
            if (V >= 0 && V < H) {                // uniform (seg edges only)
                float csx[12], csy[12];
                readspan(coff, csx, csy);         // center row V
                // sliding 25-sums -> centered values at product cols m0-2+i
                float xc[8], yc[8];
                float sxw = vsx[0] + vsx[1] + vsx[2] + vsx[3] + vsx[4];
                float syw = vsy[0] + vsy[1] + vsy[2] + vsy[3] + vsy[4];
#pragma unroll
                for (int i = 0; i < 8; ++i) {
                    if (i) { sxw += vsx[i + 4] - vsx[i - 1]; syw += vsy[i + 4] - vsy[i - 1]; }
                    xc[i] = csx[i + 2] - sxw * 0.04f;
                    yc[i] = csy[i + 2] - syw * 0.04f;
                }
                xc[0] *= pmA; yc[0] *= pmA; xc[1] *= pmA; yc[1] *= pmA;
                xc[6] *= pmB; yc[6] *= pmB; xc[7] *= pmB; yc[7] *= pmB;
                // products + horizontal 5-sums -> hq[slot]
                {
                    float p[8];
#pragma unroll
                    for (int i = 0; i < 8; ++i) p[i] = xc[i] * xc[i];
                    float h = p[0] + p[1] + p[2] + p[3] + p[4];
                    hq[slot][0][0] = h;
                    h += p[5] - p[0]; hq[slot][0][1] = h;
                    h += p[6] - p[1]; hq[slot][0][2] = h;
                    h += p[7] - p[2]; hq[slot][0][3] = h;
                }
                {
                    float p[8];
#pragma unroll
                    for (int i = 0; i < 8; ++i) p[i] = xc[i] * yc[i];
                    float h = p[0] + p[1] + p[2] + p[3] + p[4];
                    hq[slot][1][0] = h;
                    h += p[5] - p[0]; hq[slot][1][1] = h;
                    h += p[6] - p[1]; hq[slot][1][2] = h;
                    h += p[7] - p[2]; hq[slot][1][3] = h;
                }
                {
                    float p[8];
#pragma unroll
                    for (int i = 0; i < 8; ++i) p[i] = yc[i] * yc[i];
                    float h = p[0] + p[1] + p[2] + p[3] + p[4];
                    hq[slot][2][0] = h;
                    h += p[5] - p[0]; hq[slot][2][1] = h;
                    h += p[6] - p[1]; hq[slot][2][2] = h;
                    h += p[7] - p[2]; hq[slot][2][3] = h;
                }
            } else {
#pragma unroll
                for (int t = 0; t < 3; ++t)
#pragma unroll
                    for (int j = 0; j < 4; ++j) hq[slot][t][j] = 0.f;
            }

            if (k >= 8) {                         // uniform
                const int r = k - 8;              // output row within segment
#pragma unroll
                for (int j = 0; j < 4; ++j) {
                    float sxx = hq[0][0][j] + hq[1][0][j] + hq[2][0][j] + hq[3][0][j] + hq[4][0][j];
                    float sxy = hq[0][1][j] + hq[1][1][j] + hq[2][1][j] + hq[3][1][j] + hq[4][1][j];
                    float syy = hq[0][2][j] + hq[1][2][j] + hq[2][2][j] + hq[3][2][j] + hq[4][2][j];
                    // ncc = (Sxy/25) / (sqrt(Sxx/25)*sqrt(Syy/25) + 1e-8)
                    //     = Sxy / (sqrt(Sxx*Syy) + 25e-8)
                    float rad = fmaxf(sxx * syy, 0.f);
                    float s = sqrtf(rad) + 2.5e-7f;
                    float ncc = sxy * __builtin_amdgcn_rcpf(s);
                    atomicAdd(&acc[r * STRIPW + 4 * lane + j], ncc);
                }
            }
        }
    }

    __syncthreads();
    // writeout: mean over 3 channels
    const float inv3 = 1.f / 3.f;
    float* op = outg + (size_t)b * (H * W);
    for (int i = tid; i < HS * STRIPW / 4; i += 192) {
        float4 v = ((const float4*)acc)[i];
        v.x *= inv3; v.y *= inv3; v.z *= inv3; v.w *= inv3;
        int r = i / (STRIPW / 4);
        int c4 = i - r * (STRIPW / 4);
        *(float4*)(op + (size_t)(o0 + r) * W + s0 + c4 * 4) = v;
    }
}

extern "C" void kernel_launch(void* const* d_in, const int* in_sizes, int n_in,
                              void* d_out, int out_size, void* d_ws, size_t ws_size,
                              hipStream_t stream) {
    const float* x = (const float*)d_in[0];
    const float* y = (const float*)d_in[1];
    float* out = (float*)d_out;
    dim3 grid((H / HS) * 2, Bn);  // 64 x 16 = 1024 blocks
    zncc_ring<<<grid, 192, 0, stream>>>(x, y, out);
}